// Round 21
// baseline (55.421 us; speedup 1.0000x reference)
//
#include <hip/hip_runtime.h>

#define N_NODES 100000
#define N_EDGES 3200000
#define IN_DIM 192
#define NEG_SLOPE 0.2f

// regions: 256 nodes; k2 block = one region (merged sort + aggregate)
#define RSH 8
#define NPR 256                      // nodes per region
#define NREG2 391                    // ceil(100000/256)
#define EPB 8192                     // edges per segment (coarse -> k2 fast)
#define P1BLK ((N_EDGES + EPB - 1) / EPB)   // 391
#define BST 392                      // boundary row: 391 starts + ecnt
#define CAP2 9216                    // region capacity (mean 8184 + 5sig)
#define PROJ_WPB 8                   // waves per proj block (512 threads)
#define PROJ_BLOCKS ((N_NODES + PROJ_WPB - 1) / PROJ_WPB)  // 12500

// ---------------------------------------------------------------------------
// K1 (fused): blocks [0,P1BLK) = pass-1 sort of 8192 edges into 391 regions,
// 512 threads, SINGLE-PASS register stash (16 edges/thread, ~56 VGPR), LDS
// counting-sort, linear uint4 streamout + boundary row. Sort role runs at
// s_setprio(1) so its barrier phases win arbitration vs proj waves.
// Blocks [P1BLK,...) = projection. Entry = src<<8 | (dst & 255).
// ---------------------------------------------------------------------------
__global__ __launch_bounds__(512) void k1_proj_pass1(
    const float* __restrict__ x, const float* __restrict__ W,
    const float* __restrict__ att_src, const float* __restrict__ att_dst,
    float4* __restrict__ node_data, const int* __restrict__ ei,
    unsigned int* __restrict__ ipack, int* __restrict__ boundary)
{
    __shared__ unsigned int vpack[EPB];       // 32 KB
    __shared__ int hist[NREG2], lstart[NREG2], rankR[NREG2];  // 4.7 KB
    const int t = threadIdx.x;

    if (blockIdx.x >= P1BLK) {
        // ---------------- projection role: one 64-lane wave per node -------
        const int wave = (blockIdx.x - P1BLK) * PROJ_WPB + (t >> 6);
        const int lane = t & 63;
        if (wave >= N_NODES) return;
        float p0 = 0.f, p1 = 0.f;
        if (lane < 48) {
            const float4 xv = *reinterpret_cast<const float4*>(x + (size_t)wave * IN_DIM + lane * 4);
            const float* Wr = W + lane * 4 * 2;   // W is [192][2] row-major
            p0 = xv.x * Wr[0] + xv.y * Wr[2] + xv.z * Wr[4] + xv.w * Wr[6];
            p1 = xv.x * Wr[1] + xv.y * Wr[3] + xv.z * Wr[5] + xv.w * Wr[7];
        }
        #pragma unroll
        for (int off = 32; off >= 1; off >>= 1) {
            p0 += __shfl_down(p0, off, 64);
            p1 += __shfl_down(p1, off, 64);
        }
        if (lane == 0) {
            const float as = p0 * att_src[0] + p1 * att_src[1];
            const float ad = p0 * att_dst[0] + p1 * att_dst[1];
            node_data[wave] = make_float4(p0, p1, as, ad);
        }
        return;
    }

    // ---- pass-1 sort role (8192 edges, 16/thread, single-pass stash) ----
    for (int i = t; i < NREG2; i += 512) hist[i] = 0;
    __syncthreads();
    __builtin_amdgcn_s_setprio(1);

    const int e0 = blockIdx.x * EPB;
    const int ecnt = min(EPB, N_EDGES - e0);   // multiple of 4
    int ss[16], dd[16];
    bool ok[4];
    #pragma unroll
    for (int j = 0; j < 4; ++j) {
        const int e = e0 + (j * 512 + t) * 4;
        ok[j] = (e < N_EDGES);
        if (ok[j]) {
            const int4 s4 = *reinterpret_cast<const int4*>(ei + e);
            const int4 d4 = *reinterpret_cast<const int4*>(ei + N_EDGES + e);
            ss[j*4+0] = s4.x; ss[j*4+1] = s4.y; ss[j*4+2] = s4.z; ss[j*4+3] = s4.w;
            dd[j*4+0] = d4.x; dd[j*4+1] = d4.y; dd[j*4+2] = d4.z; dd[j*4+3] = d4.w;
            atomicAdd(&hist[d4.x >> RSH], 1);
            atomicAdd(&hist[d4.y >> RSH], 1);
            atomicAdd(&hist[d4.z >> RSH], 1);
            atomicAdd(&hist[d4.w >> RSH], 1);
        } else {
            #pragma unroll
            for (int k = 0; k < 4; ++k) { ss[j*4+k] = 0; dd[j*4+k] = 0; }
        }
    }
    __syncthreads();

    // single-wave exclusive scan over 391 bins (7 chunks of 64, carry)
    if (t < 64) {
        int carry = 0;
        #pragma unroll
        for (int c = 0; c < 7; ++c) {
            const int idx = c * 64 + t;
            const int v = (idx < NREG2) ? hist[idx] : 0;
            int s = v;
            #pragma unroll
            for (int off = 1; off < 64; off <<= 1) {
                const int u = __shfl_up(s, off, 64);
                if (t >= off) s += u;
            }
            if (idx < NREG2) lstart[idx] = carry + s - v;
            carry += __shfl(s, 63, 64);
        }
    }
    __syncthreads();
    if (t < NREG2) {
        rankR[t] = 0;
        boundary[blockIdx.x * BST + t] = lstart[t];
    }
    if (t == NREG2) boundary[blockIdx.x * BST + NREG2] = ecnt;
    __syncthreads();

    // place from stash into LDS in region order
    #pragma unroll
    for (int j = 0; j < 4; ++j) {
        if (ok[j]) {
            #pragma unroll
            for (int k = 0; k < 4; ++k) {
                const int s = ss[j*4+k], d = dd[j*4+k];
                const int r = d >> RSH;
                const int rk = atomicAdd(&rankR[r], 1);
                vpack[lstart[r] + rk] =
                    ((unsigned int)s << 8) | (unsigned int)(d & 255);
            }
        }
    }
    __syncthreads();

    // pure linear uint4 stream-out
    for (int i4 = t * 4; i4 < ecnt; i4 += 512 * 4)
        *reinterpret_cast<uint4*>(&ipack[e0 + i4]) =
            *reinterpret_cast<const uint4*>(&vpack[i4]);
    __builtin_amdgcn_s_setprio(0);
}

// ---------------------------------------------------------------------------
// K2 (merged pass-2 + aggregate) — R18/R20 version verbatim (proven ~13 us).
// One block per 256-node region: segment prefix via one wave, address-table
// gather, counting-sort by node, atomic-free accumulation, finalize.
// ---------------------------------------------------------------------------
__global__ __launch_bounds__(1024) void k2_region_agg(
    const unsigned int* __restrict__ ipack, const int* __restrict__ boundary,
    const float4* __restrict__ node_data, const float* __restrict__ bias,
    float* __restrict__ out)
{
    __shared__ unsigned int vals[CAP2];        // 36 KB: addr table, then srcs
    __shared__ int slen[P1BLK], sbase[P1BLK];
    __shared__ int spre[P1BLK + 1];
    __shared__ int histN[NPR], startN[NPR], rankN[NPR];
    __shared__ float adst[NPR];
    __shared__ float part0[1024], part1[1024], partw[1024];  // 12 KB
    const int r = blockIdx.x, t = threadIdx.x;

    if (t < NPR) {
        const int n = r * NPR + t;
        histN[t] = 0; rankN[t] = 0;
        adst[t] = (n < N_NODES) ? node_data[n].w : 0.f;
    }
    if (t < P1BLK) {
        const int b0 = boundary[t * BST + r];
        const int b1 = boundary[t * BST + r + 1];
        slen[t]  = b1 - b0;
        sbase[t] = t * EPB + b0;
    }
    __syncthreads();

    // single-wave exclusive prefix over 391 segment lengths
    if (t < 64) {
        int carry = 0;
        #pragma unroll
        for (int c = 0; c < 7; ++c) {
            const int idx = c * 64 + t;
            const int v = (idx < P1BLK) ? slen[idx] : 0;
            int s = v;
            #pragma unroll
            for (int off = 1; off < 64; off <<= 1) {
                const int u = __shfl_up(s, off, 64);
                if (t >= off) s += u;
            }
            if (idx < P1BLK) spre[idx] = carry + s - v;
            carry += __shfl(s, 63, 64);
        }
        if (t == 0) spre[P1BLK] = carry;
    }
    __syncthreads();
    const int total = min(spre[P1BLK], CAP2);

    // fill address table: vals[i] = global ipack index for entry i
    for (int s2 = t; s2 < P1BLK; s2 += 1024) {
        int b0 = spre[s2];
        int len = slen[s2];
        if (b0 < CAP2) {
            if (b0 + len > CAP2) len = CAP2 - b0;
            const int gb = sbase[s2];
            for (int k = 0; k < len; ++k) vals[b0 + k] = (unsigned int)(gb + k);
        }
    }
    __syncthreads();

    // gather via address table, decode, histogram by node
    unsigned int ent[9];
    int nl[9];
    #pragma unroll
    for (int j = 0; j < 9; ++j) {
        const int i = t + j * 1024;
        if (i < total) {
            const unsigned int e = ipack[vals[i]];
            ent[j] = e >> 8;                 // src
            nl[j]  = (int)(e & 255u);        // node-local
            atomicAdd(&histN[nl[j]], 1);
        } else nl[j] = -1;
    }
    __syncthreads();

    // exclusive scan of histN (256) by wave 0, 4 chunks with carry
    if (t < 64) {
        int carry = 0;
        #pragma unroll
        for (int c2 = 0; c2 < 4; ++c2) {
            const int idx = c2 * 64 + t;
            const int v = histN[idx];
            int s = v;
            #pragma unroll
            for (int off = 1; off < 64; off <<= 1) {
                const int u = __shfl_up(s, off, 64);
                if (t >= off) s += u;
            }
            startN[idx] = carry + s - v;
            carry += __shfl(s, 63, 64);
        }
    }
    __syncthreads();

    // place srcs grouped by node (overwrites address table - all reads done)
    #pragma unroll
    for (int j = 0; j < 9; ++j) {
        if (nl[j] >= 0) {
            const int rk = atomicAdd(&rankN[nl[j]], 1);
            vals[startN[nl[j]] + rk] = ent[j];
        }
    }
    __syncthreads();

    // atomic-free accumulate: thread t owns node t&255, slice t>>8 (4 slices)
    {
        const int node = t & 255, sl = t >> 8;
        const float ad = adst[node];
        const int rs = startN[node], re = rs + histN[node];
        float s0 = 0.f, s1 = 0.f, sw = 0.f;
        for (int i = rs + sl; i < re; i += 4) {
            const int src = (int)vals[i];
            const float4 nd = node_data[src];
            float a = nd.z + ad;
            a = (a >= 0.f) ? a : NEG_SLOPE * a;
            const float w = __expf(a);
            s0 += w * nd.x; s1 += w * nd.y; sw += w;
        }
        part0[t] = s0; part1[t] = s1; partw[t] = sw;
    }
    __syncthreads();

    // merge 4 slices + self-loop + bias, coalesced write
    if (t < NPR) {
        const int n = r * NPR + t;
        if (n < N_NODES) {
            const float A0 = part0[t] + part0[t + 256] + part0[t + 512] + part0[t + 768];
            const float A1 = part1[t] + part1[t + 256] + part1[t + 512] + part1[t + 768];
            const float AW = partw[t] + partw[t + 256] + partw[t + 512] + partw[t + 768];
            const float4 nd = node_data[n];
            float a = nd.z + nd.w;               // self-loop logit
            a = (a >= 0.f) ? a : NEG_SLOPE * a;
            const float w = __expf(a);
            const float den = AW + w + 1e-16f;
            const float o0 = (A0 + w * nd.x) / den + bias[0];
            const float o1 = (A1 + w * nd.y) / den + bias[1];
            *reinterpret_cast<float2*>(out + (size_t)n * 2) = make_float2(o0, o1);
        }
    }
}

// ------------------- last-resort fallback (round-2 path) -------------------
__global__ __launch_bounds__(256) void proj_kernel(
    const float* __restrict__ x, const float* __restrict__ W,
    const float* __restrict__ att_src, const float* __restrict__ att_dst,
    float4* __restrict__ node_data, float4* __restrict__ accum)
{
    const int wave = (blockIdx.x * blockDim.x + threadIdx.x) >> 6;
    const int lane = threadIdx.x & 63;
    if (wave >= N_NODES) return;
    float p0 = 0.f, p1 = 0.f;
    if (lane < 48) {
        const float4 xv = *reinterpret_cast<const float4*>(x + (size_t)wave * IN_DIM + lane * 4);
        const float* Wr = W + lane * 4 * 2;
        p0 = xv.x * Wr[0] + xv.y * Wr[2] + xv.z * Wr[4] + xv.w * Wr[6];
        p1 = xv.x * Wr[1] + xv.y * Wr[3] + xv.z * Wr[5] + xv.w * Wr[7];
    }
    #pragma unroll
    for (int off = 32; off >= 1; off >>= 1) {
        p0 += __shfl_down(p0, off, 64);
        p1 += __shfl_down(p1, off, 64);
    }
    if (lane == 0) {
        const float as = p0 * att_src[0] + p1 * att_src[1];
        const float ad = p0 * att_dst[0] + p1 * att_dst[1];
        node_data[wave] = make_float4(p0, p1, as, ad);
        if (accum) accum[wave] = make_float4(0.f, 0.f, 0.f, 0.f);
    }
}

__global__ __launch_bounds__(256) void edge_kernel_atomic(
    const int* __restrict__ ei, const float4* __restrict__ node_data,
    float* __restrict__ accum)
{
    const int t = blockIdx.x * blockDim.x + threadIdx.x;
    const int base = t * 4;
    if (base >= N_EDGES) return;
    const int4 s4 = *reinterpret_cast<const int4*>(ei + base);
    const int4 d4 = *reinterpret_cast<const int4*>(ei + N_EDGES + base);
    const int ss[4] = {s4.x, s4.y, s4.z, s4.w};
    const int dd[4] = {d4.x, d4.y, d4.z, d4.w};
    #pragma unroll
    for (int k = 0; k < 4; ++k) {
        const int s = ss[k], d = dd[k];
        const float4 nds = node_data[s];
        const float ad = reinterpret_cast<const float*>(node_data)[d * 4 + 3];
        float a = nds.z + ad;
        a = (a >= 0.f) ? a : NEG_SLOPE * a;
        const float w = __expf(a);
        atomicAdd(&accum[d * 4 + 0], w * nds.x);
        atomicAdd(&accum[d * 4 + 1], w * nds.y);
        atomicAdd(&accum[d * 4 + 2], w);
    }
}

__global__ __launch_bounds__(256) void finalize_kernel(
    const float4* __restrict__ node_data, const float4* __restrict__ accum,
    const float* __restrict__ bias, float* __restrict__ out)
{
    const int n = blockIdx.x * blockDim.x + threadIdx.x;
    if (n >= N_NODES) return;
    const float4 nd = node_data[n];
    const float4 ac = accum[n];
    float a = nd.z + nd.w;
    a = (a >= 0.f) ? a : NEG_SLOPE * a;
    const float w = __expf(a);
    const float den = ac.z + w + 1e-16f;
    const float o0 = (ac.x + w * nd.x) / den + bias[0];
    const float o1 = (ac.y + w * nd.y) / den + bias[1];
    *reinterpret_cast<float2*>(out + (size_t)n * 2) = make_float2(o0, o1);
}

extern "C" void kernel_launch(void* const* d_in, const int* in_sizes, int n_in,
                              void* d_out, int out_size, void* d_ws, size_t ws_size,
                              hipStream_t stream) {
    const float* x       = (const float*)d_in[0];
    const int*   ei      = (const int*)d_in[1];
    const float* W       = (const float*)d_in[3];
    const float* att_src = (const float*)d_in[4];
    const float* att_dst = (const float*)d_in[5];
    const float* bias    = (const float*)d_in[6];
    float* out = (float*)d_out;

    char* p = (char*)d_ws;
    float4* node_data = (float4*)p;            p += (size_t)N_NODES * 16;        // 1.6 MB
    unsigned int* ipack = (unsigned int*)p;    p += (size_t)P1BLK * EPB * 4;     // 12.8 MB
    int* boundary = (int*)p;                   p += (size_t)P1BLK * BST * 4;     // 613 KB
    const size_t need = (size_t)(p - (char*)d_ws);

    if (ws_size >= need) {
        k1_proj_pass1<<<P1BLK + PROJ_BLOCKS, 512, 0, stream>>>(
            x, W, att_src, att_dst, node_data, ei, ipack, boundary);
        k2_region_agg<<<NREG2, 1024, 0, stream>>>(ipack, boundary, node_data, bias, out);
    } else {
        float4* nd2 = (float4*)d_ws;
        float4* accum = nd2 + N_NODES;
        proj_kernel<<<(N_NODES + 3) / 4, 256, 0, stream>>>(x, W, att_src, att_dst, nd2, accum);
        edge_kernel_atomic<<<(N_EDGES / 4 + 255) / 256, 256, 0, stream>>>(ei, nd2, (float*)accum);
        finalize_kernel<<<(N_NODES + 255) / 256, 256, 0, stream>>>(nd2, accum, bias, out);
    }
}

// Round 22
// 53.736 us; speedup vs baseline: 1.0314x; 1.0314x over previous
//
#include <hip/hip_runtime.h>

#define N_NODES 100000
#define N_EDGES 3200000
#define IN_DIM 192
#define NEG_SLOPE 0.2f

// regions: 256 nodes; k2 block = one region (merged sort + aggregate)
#define RSH 8
#define NPR 256                      // nodes per region
#define NREG2 391                    // ceil(100000/256)
#define EPB 8192                     // edges per segment (coarse -> k2 fast)
#define P1BLK ((N_EDGES + EPB - 1) / EPB)   // 391
#define BST 392                      // boundary row: 391 starts + ecnt
#define CAP2 9216                    // region capacity (mean 8184 + 5sig)
#define PROJ_WPB 8                   // waves per proj block (512 threads)
#define PROJ_BLOCKS ((N_NODES + PROJ_WPB - 1) / PROJ_WPB)  // 12500

// ---------------------------------------------------------------------------
// K1 (fused): blocks [0,P1BLK) = pass-1 sort of 8192 edges into 391 regions
// using 512 threads (8 waves -> 4 blocks/CU). Two-pass load (histogram, then
// re-place from L2) keeps VGPRs low. Block-private segment, linear uint4
// streamout + boundary row. Blocks [P1BLK,...) = projection.
// Entry = src<<8 | (dst & 255). Zero global atomics anywhere.
// ---------------------------------------------------------------------------
__global__ __launch_bounds__(512) void k1_proj_pass1(
    const float* __restrict__ x, const float* __restrict__ W,
    const float* __restrict__ att_src, const float* __restrict__ att_dst,
    float4* __restrict__ node_data, const int* __restrict__ ei,
    unsigned int* __restrict__ ipack, int* __restrict__ boundary)
{
    __shared__ unsigned int vpack[EPB];       // 32 KB
    __shared__ int hist[NREG2], lstart[NREG2], rankR[NREG2];  // 4.7 KB
    const int t = threadIdx.x;

    if (blockIdx.x >= P1BLK) {
        // ---------------- projection role: one 64-lane wave per node -------
        const int wave = (blockIdx.x - P1BLK) * PROJ_WPB + (t >> 6);
        const int lane = t & 63;
        if (wave >= N_NODES) return;
        float p0 = 0.f, p1 = 0.f;
        if (lane < 48) {
            const float4 xv = *reinterpret_cast<const float4*>(x + (size_t)wave * IN_DIM + lane * 4);
            const float* Wr = W + lane * 4 * 2;   // W is [192][2] row-major
            p0 = xv.x * Wr[0] + xv.y * Wr[2] + xv.z * Wr[4] + xv.w * Wr[6];
            p1 = xv.x * Wr[1] + xv.y * Wr[3] + xv.z * Wr[5] + xv.w * Wr[7];
        }
        #pragma unroll
        for (int off = 32; off >= 1; off >>= 1) {
            p0 += __shfl_down(p0, off, 64);
            p1 += __shfl_down(p1, off, 64);
        }
        if (lane == 0) {
            const float as = p0 * att_src[0] + p1 * att_src[1];
            const float ad = p0 * att_dst[0] + p1 * att_dst[1];
            node_data[wave] = make_float4(p0, p1, as, ad);
        }
        return;
    }

    // ---- pass-1 sort role (8192 edges, 16 per thread, two-pass) ----
    for (int i = t; i < NREG2; i += 512) hist[i] = 0;
    __syncthreads();

    const int e0 = blockIdx.x * EPB;
    const int ecnt = min(EPB, N_EDGES - e0);   // multiple of 4

    // Phase A: histogram only (no register stash)
    #pragma unroll
    for (int j = 0; j < 4; ++j) {
        const int e = e0 + (j * 512 + t) * 4;
        if (e < N_EDGES) {
            const int4 d4 = *reinterpret_cast<const int4*>(ei + N_EDGES + e);
            atomicAdd(&hist[d4.x >> RSH], 1);
            atomicAdd(&hist[d4.y >> RSH], 1);
            atomicAdd(&hist[d4.z >> RSH], 1);
            atomicAdd(&hist[d4.w >> RSH], 1);
        }
    }
    __syncthreads();

    // single-wave exclusive scan over 391 bins (7 chunks of 64, carry)
    if (t < 64) {
        int carry = 0;
        #pragma unroll
        for (int c = 0; c < 7; ++c) {
            const int idx = c * 64 + t;
            const int v = (idx < NREG2) ? hist[idx] : 0;
            int s = v;
            #pragma unroll
            for (int off = 1; off < 64; off <<= 1) {
                const int u = __shfl_up(s, off, 64);
                if (t >= off) s += u;
            }
            if (idx < NREG2) lstart[idx] = carry + s - v;
            carry += __shfl(s, 63, 64);
        }
    }
    __syncthreads();
    if (t < NREG2) {
        rankR[t] = 0;
        boundary[blockIdx.x * BST + t] = lstart[t];
    }
    if (t == NREG2) boundary[blockIdx.x * BST + NREG2] = ecnt;
    __syncthreads();

    // Phase C: re-load (L2-hot) and place into LDS in region order
    #pragma unroll
    for (int j = 0; j < 4; ++j) {
        const int e = e0 + (j * 512 + t) * 4;
        if (e < N_EDGES) {
            const int4 s4 = *reinterpret_cast<const int4*>(ei + e);
            const int4 d4 = *reinterpret_cast<const int4*>(ei + N_EDGES + e);
            const int ss[4] = {s4.x, s4.y, s4.z, s4.w};
            const int dd[4] = {d4.x, d4.y, d4.z, d4.w};
            #pragma unroll
            for (int k = 0; k < 4; ++k) {
                const int r = dd[k] >> RSH;
                const int rk = atomicAdd(&rankR[r], 1);
                vpack[lstart[r] + rk] =
                    ((unsigned int)ss[k] << 8) | (unsigned int)(dd[k] & 255);
            }
        }
    }
    __syncthreads();

    // Phase D: pure linear uint4 stream-out
    for (int i4 = t * 4; i4 < ecnt; i4 += 512 * 4)
        *reinterpret_cast<uint4*>(&ipack[e0 + i4]) =
            *reinterpret_cast<const uint4*>(&vpack[i4]);
}

// ---------------------------------------------------------------------------
// K2 (merged pass-2 + aggregate) — proven ~13 us version.
// One block per 256-node region: segment prefix via one wave, address-table
// gather, counting-sort by node, atomic-free accumulation, finalize.
// ---------------------------------------------------------------------------
__global__ __launch_bounds__(1024) void k2_region_agg(
    const unsigned int* __restrict__ ipack, const int* __restrict__ boundary,
    const float4* __restrict__ node_data, const float* __restrict__ bias,
    float* __restrict__ out)
{
    __shared__ unsigned int vals[CAP2];        // 36 KB: addr table, then srcs
    __shared__ int slen[P1BLK], sbase[P1BLK];
    __shared__ int spre[P1BLK + 1];
    __shared__ int histN[NPR], startN[NPR], rankN[NPR];
    __shared__ float adst[NPR];
    __shared__ float part0[1024], part1[1024], partw[1024];  // 12 KB
    const int r = blockIdx.x, t = threadIdx.x;

    if (t < NPR) {
        const int n = r * NPR + t;
        histN[t] = 0; rankN[t] = 0;
        adst[t] = (n < N_NODES) ? node_data[n].w : 0.f;
    }
    if (t < P1BLK) {
        const int b0 = boundary[t * BST + r];
        const int b1 = boundary[t * BST + r + 1];
        slen[t]  = b1 - b0;
        sbase[t] = t * EPB + b0;
    }
    __syncthreads();

    // single-wave exclusive prefix over 391 segment lengths
    if (t < 64) {
        int carry = 0;
        #pragma unroll
        for (int c = 0; c < 7; ++c) {
            const int idx = c * 64 + t;
            const int v = (idx < P1BLK) ? slen[idx] : 0;
            int s = v;
            #pragma unroll
            for (int off = 1; off < 64; off <<= 1) {
                const int u = __shfl_up(s, off, 64);
                if (t >= off) s += u;
            }
            if (idx < P1BLK) spre[idx] = carry + s - v;
            carry += __shfl(s, 63, 64);
        }
        if (t == 0) spre[P1BLK] = carry;
    }
    __syncthreads();
    const int total = min(spre[P1BLK], CAP2);

    // fill address table: vals[i] = global ipack index for entry i
    for (int s2 = t; s2 < P1BLK; s2 += 1024) {
        int b0 = spre[s2];
        int len = slen[s2];
        if (b0 < CAP2) {
            if (b0 + len > CAP2) len = CAP2 - b0;
            const int gb = sbase[s2];
            for (int k = 0; k < len; ++k) vals[b0 + k] = (unsigned int)(gb + k);
        }
    }
    __syncthreads();

    // gather via address table, decode, histogram by node
    unsigned int ent[9];
    int nl[9];
    #pragma unroll
    for (int j = 0; j < 9; ++j) {
        const int i = t + j * 1024;
        if (i < total) {
            const unsigned int e = ipack[vals[i]];
            ent[j] = e >> 8;                 // src
            nl[j]  = (int)(e & 255u);        // node-local
            atomicAdd(&histN[nl[j]], 1);
        } else nl[j] = -1;
    }
    __syncthreads();

    // exclusive scan of histN (256) by wave 0, 4 chunks with carry
    if (t < 64) {
        int carry = 0;
        #pragma unroll
        for (int c2 = 0; c2 < 4; ++c2) {
            const int idx = c2 * 64 + t;
            const int v = histN[idx];
            int s = v;
            #pragma unroll
            for (int off = 1; off < 64; off <<= 1) {
                const int u = __shfl_up(s, off, 64);
                if (t >= off) s += u;
            }
            startN[idx] = carry + s - v;
            carry += __shfl(s, 63, 64);
        }
    }
    __syncthreads();

    // place srcs grouped by node (overwrites address table - all reads done)
    #pragma unroll
    for (int j = 0; j < 9; ++j) {
        if (nl[j] >= 0) {
            const int rk = atomicAdd(&rankN[nl[j]], 1);
            vals[startN[nl[j]] + rk] = ent[j];
        }
    }
    __syncthreads();

    // atomic-free accumulate: thread t owns node t&255, slice t>>8 (4 slices)
    {
        const int node = t & 255, sl = t >> 8;
        const float ad = adst[node];
        const int rs = startN[node], re = rs + histN[node];
        float s0 = 0.f, s1 = 0.f, sw = 0.f;
        for (int i = rs + sl; i < re; i += 4) {
            const int src = (int)vals[i];
            const float4 nd = node_data[src];
            float a = nd.z + ad;
            a = (a >= 0.f) ? a : NEG_SLOPE * a;
            const float w = __expf(a);
            s0 += w * nd.x; s1 += w * nd.y; sw += w;
        }
        part0[t] = s0; part1[t] = s1; partw[t] = sw;
    }
    __syncthreads();

    // merge 4 slices + self-loop + bias, coalesced write
    if (t < NPR) {
        const int n = r * NPR + t;
        if (n < N_NODES) {
            const float A0 = part0[t] + part0[t + 256] + part0[t + 512] + part0[t + 768];
            const float A1 = part1[t] + part1[t + 256] + part1[t + 512] + part1[t + 768];
            const float AW = partw[t] + partw[t + 256] + partw[t + 512] + partw[t + 768];
            const float4 nd = node_data[n];
            float a = nd.z + nd.w;               // self-loop logit
            a = (a >= 0.f) ? a : NEG_SLOPE * a;
            const float w = __expf(a);
            const float den = AW + w + 1e-16f;
            const float o0 = (A0 + w * nd.x) / den + bias[0];
            const float o1 = (A1 + w * nd.y) / den + bias[1];
            *reinterpret_cast<float2*>(out + (size_t)n * 2) = make_float2(o0, o1);
        }
    }
}

// ------------------- last-resort fallback (round-2 path) -------------------
__global__ __launch_bounds__(256) void proj_kernel(
    const float* __restrict__ x, const float* __restrict__ W,
    const float* __restrict__ att_src, const float* __restrict__ att_dst,
    float4* __restrict__ node_data, float4* __restrict__ accum)
{
    const int wave = (blockIdx.x * blockDim.x + threadIdx.x) >> 6;
    const int lane = threadIdx.x & 63;
    if (wave >= N_NODES) return;
    float p0 = 0.f, p1 = 0.f;
    if (lane < 48) {
        const float4 xv = *reinterpret_cast<const float4*>(x + (size_t)wave * IN_DIM + lane * 4);
        const float* Wr = W + lane * 4 * 2;
        p0 = xv.x * Wr[0] + xv.y * Wr[2] + xv.z * Wr[4] + xv.w * Wr[6];
        p1 = xv.x * Wr[1] + xv.y * Wr[3] + xv.z * Wr[5] + xv.w * Wr[7];
    }
    #pragma unroll
    for (int off = 32; off >= 1; off >>= 1) {
        p0 += __shfl_down(p0, off, 64);
        p1 += __shfl_down(p1, off, 64);
    }
    if (lane == 0) {
        const float as = p0 * att_src[0] + p1 * att_src[1];
        const float ad = p0 * att_dst[0] + p1 * att_dst[1];
        node_data[wave] = make_float4(p0, p1, as, ad);
        if (accum) accum[wave] = make_float4(0.f, 0.f, 0.f, 0.f);
    }
}

__global__ __launch_bounds__(256) void edge_kernel_atomic(
    const int* __restrict__ ei, const float4* __restrict__ node_data,
    float* __restrict__ accum)
{
    const int t = blockIdx.x * blockDim.x + threadIdx.x;
    const int base = t * 4;
    if (base >= N_EDGES) return;
    const int4 s4 = *reinterpret_cast<const int4*>(ei + base);
    const int4 d4 = *reinterpret_cast<const int4*>(ei + N_EDGES + base);
    const int ss[4] = {s4.x, s4.y, s4.z, s4.w};
    const int dd[4] = {d4.x, d4.y, d4.z, d4.w};
    #pragma unroll
    for (int k = 0; k < 4; ++k) {
        const int s = ss[k], d = dd[k];
        const float4 nds = node_data[s];
        const float ad = reinterpret_cast<const float*>(node_data)[d * 4 + 3];
        float a = nds.z + ad;
        a = (a >= 0.f) ? a : NEG_SLOPE * a;
        const float w = __expf(a);
        atomicAdd(&accum[d * 4 + 0], w * nds.x);
        atomicAdd(&accum[d * 4 + 1], w * nds.y);
        atomicAdd(&accum[d * 4 + 2], w);
    }
}

__global__ __launch_bounds__(256) void finalize_kernel(
    const float4* __restrict__ node_data, const float4* __restrict__ accum,
    const float* __restrict__ bias, float* __restrict__ out)
{
    const int n = blockIdx.x * blockDim.x + threadIdx.x;
    if (n >= N_NODES) return;
    const float4 nd = node_data[n];
    const float4 ac = accum[n];
    float a = nd.z + nd.w;
    a = (a >= 0.f) ? a : NEG_SLOPE * a;
    const float w = __expf(a);
    const float den = ac.z + w + 1e-16f;
    const float o0 = (ac.x + w * nd.x) / den + bias[0];
    const float o1 = (ac.y + w * nd.y) / den + bias[1];
    *reinterpret_cast<float2*>(out + (size_t)n * 2) = make_float2(o0, o1);
}

extern "C" void kernel_launch(void* const* d_in, const int* in_sizes, int n_in,
                              void* d_out, int out_size, void* d_ws, size_t ws_size,
                              hipStream_t stream) {
    const float* x       = (const float*)d_in[0];
    const int*   ei      = (const int*)d_in[1];
    const float* W       = (const float*)d_in[3];
    const float* att_src = (const float*)d_in[4];
    const float* att_dst = (const float*)d_in[5];
    const float* bias    = (const float*)d_in[6];
    float* out = (float*)d_out;

    char* p = (char*)d_ws;
    float4* node_data = (float4*)p;            p += (size_t)N_NODES * 16;        // 1.6 MB
    unsigned int* ipack = (unsigned int*)p;    p += (size_t)P1BLK * EPB * 4;     // 12.8 MB
    int* boundary = (int*)p;                   p += (size_t)P1BLK * BST * 4;     // 613 KB
    const size_t need = (size_t)(p - (char*)d_ws);

    if (ws_size >= need) {
        k1_proj_pass1<<<P1BLK + PROJ_BLOCKS, 512, 0, stream>>>(
            x, W, att_src, att_dst, node_data, ei, ipack, boundary);
        k2_region_agg<<<NREG2, 1024, 0, stream>>>(ipack, boundary, node_data, bias, out);
    } else {
        float4* nd2 = (float4*)d_ws;
        float4* accum = nd2 + N_NODES;
        proj_kernel<<<(N_NODES + 3) / 4, 256, 0, stream>>>(x, W, att_src, att_dst, nd2, accum);
        edge_kernel_atomic<<<(N_EDGES / 4 + 255) / 256, 256, 0, stream>>>(ei, nd2, (float*)accum);
        finalize_kernel<<<(N_NODES + 255) / 256, 256, 0, stream>>>(nd2, accum, bias, out);
    }
}